// Round 1
// baseline (654.822 us; speedup 1.0000x reference)
//
#include <hip/hip_runtime.h>
#include <math.h>

#define N_NODES 50000
#define N_EDGES 800000
#define DD 64
#define EPSV 1e-5f
#define PROJ_NT 64

// ---------------- CSR build ----------------

__global__ __launch_bounds__(256) void count_kernel(const int* __restrict__ dst,
                                                    int* __restrict__ cnt) {
    int e = blockIdx.x * 256 + threadIdx.x;
    if (e < N_EDGES) atomicAdd(&cnt[dst[e]], 1);
}

// single-block chunked Hillis-Steele exclusive scan; also initializes cursor
__global__ __launch_bounds__(1024) void scan_kernel(int* __restrict__ cnt_cursor,
                                                    int* __restrict__ row_off) {
    __shared__ int buf[1024];
    __shared__ int carry_s;
    if (threadIdx.x == 0) carry_s = 0;
    __syncthreads();
    for (int base = 0; base < N_NODES; base += 1024) {
        int i = base + threadIdx.x;
        int v = (i < N_NODES) ? cnt_cursor[i] : 0;
        buf[threadIdx.x] = v;
        __syncthreads();
        for (int off = 1; off < 1024; off <<= 1) {
            int tv = (threadIdx.x >= off) ? buf[threadIdx.x - off] : 0;
            __syncthreads();
            buf[threadIdx.x] += tv;
            __syncthreads();
        }
        int excl  = buf[threadIdx.x] - v;
        int total = buf[1023];
        int carry = carry_s;
        __syncthreads();
        if (i < N_NODES) {
            row_off[i]    = carry + excl;
            cnt_cursor[i] = carry + excl;   // cursor for scatter
        }
        if (threadIdx.x == 0) carry_s = carry + total;
        __syncthreads();
    }
    if (threadIdx.x == 0) row_off[N_NODES] = N_EDGES;
}

__global__ __launch_bounds__(256) void scatter_kernel(const int* __restrict__ src,
                                                      const int* __restrict__ dst,
                                                      int* __restrict__ cursor,
                                                      int* __restrict__ ssrc,
                                                      int* __restrict__ sdst) {
    int e = blockIdx.x * 256 + threadIdx.x;
    if (e < N_EDGES) {
        int d = dst[e];
        int p = atomicAdd(&cursor[d], 1);
        ssrc[p] = src[e];
        sdst[p] = d;
    }
}

// ---------------- projections (+ fused BN/ReLU on input) ----------------
// block 256: wave m in {q,k,v,skip}, lane c = output col. W column in VGPRs,
// x tile staged in LDS (16 nodes at a time).
template<bool BN>
__global__ __launch_bounds__(256) void proj_kernel(
    const float* __restrict__ hin,
    const float* __restrict__ Wq, const float* __restrict__ Wk,
    const float* __restrict__ Wv, const float* __restrict__ Ws,
    const float* __restrict__ bq, const float* __restrict__ bk,
    const float* __restrict__ bv, const float* __restrict__ bs,
    const float* __restrict__ bnp, const float* __restrict__ gamma,
    const float* __restrict__ beta,
    float* __restrict__ qb, float* __restrict__ kb,
    float* __restrict__ vb, float* __restrict__ skb)
{
    __shared__ float xs[16][64];
    const int t = threadIdx.x;
    const int m = t >> 6, c = t & 63;
    const float* Wm = (m == 0) ? Wq : (m == 1) ? Wk : (m == 2) ? Wv : Ws;
    const float* bm = (m == 0) ? bq : (m == 1) ? bk : (m == 2) ? bv : bs;
    float* outp     = (m == 0) ? qb : (m == 1) ? kb : (m == 2) ? vb : skb;

    float w[64];
#pragma unroll
    for (int i = 0; i < 64; i++) w[i] = Wm[i * 64 + c];   // coalesced per wave
    const float bias = bm[c];

    const int jj = t >> 4, i0 = (t & 15) * 4;
    float4 mu4, rs4, ga4, be4;
    if (BN) {
        mu4 = *(const float4*)&bnp[i0];
        rs4 = *(const float4*)&bnp[64 + i0];
        ga4 = *(const float4*)&gamma[i0];
        be4 = *(const float4*)&beta[i0];
    }

    const int nbase = blockIdx.x * PROJ_NT;
    for (int tile = 0; tile < PROJ_NT / 16; ++tile) {
        const int n0 = nbase + tile * 16;
        __syncthreads();
        {
            int node = n0 + jj;
            float4 xv = make_float4(0.f, 0.f, 0.f, 0.f);
            if (node < N_NODES) xv = *(const float4*)&hin[node * 64 + i0];
            if (BN) {
                xv.x = fmaxf(fmaf(ga4.x * (xv.x - mu4.x), rs4.x, be4.x), 0.f);
                xv.y = fmaxf(fmaf(ga4.y * (xv.y - mu4.y), rs4.y, be4.y), 0.f);
                xv.z = fmaxf(fmaf(ga4.z * (xv.z - mu4.z), rs4.z, be4.z), 0.f);
                xv.w = fmaxf(fmaf(ga4.w * (xv.w - mu4.w), rs4.w, be4.w), 0.f);
            }
            *(float4*)&xs[jj][i0] = xv;
        }
        __syncthreads();
#pragma unroll 4
        for (int j = 0; j < 16; j++) {
            const int node = n0 + j;
            if (node >= N_NODES) break;   // uniform across block
            float a0 = bias, a1 = 0.f, a2 = 0.f, a3 = 0.f;
#pragma unroll
            for (int i4 = 0; i4 < 16; i4++) {
                float4 xv = *(const float4*)&xs[j][i4 * 4];
                a0 = fmaf(xv.x, w[i4 * 4 + 0], a0);
                a1 = fmaf(xv.y, w[i4 * 4 + 1], a1);
                a2 = fmaf(xv.z, w[i4 * 4 + 2], a2);
                a3 = fmaf(xv.w, w[i4 * 4 + 3], a3);
            }
            outp[node * 64 + c] = (a0 + a1) + (a2 + a3);
        }
    }
}

// ---------------- edge scores ----------------
// 8 threads per edge, 2 float4 per side, shfl reduce.
__global__ __launch_bounds__(256) void edge_kernel(const float* __restrict__ qb,
                                                   const float* __restrict__ kb,
                                                   const int* __restrict__ sdst,
                                                   const int* __restrict__ ssrc,
                                                   float* __restrict__ s_out) {
    int idx  = blockIdx.x * 256 + threadIdx.x;
    int e    = idx >> 3;
    int lane = idx & 7;
    if (e >= N_EDGES) return;
    int d = sdst[e], s = ssrc[e];
    const float4* qp = (const float4*)&qb[d * 64 + lane * 8];
    const float4* kp = (const float4*)&kb[s * 64 + lane * 8];
    float4 q0 = qp[0], q1 = qp[1];
    float4 k0 = kp[0], k1 = kp[1];
    float acc = q0.x * k0.x + q0.y * k0.y + q0.z * k0.z + q0.w * k0.w
              + q1.x * k1.x + q1.y * k1.y + q1.z * k1.z + q1.w * k1.w;
    acc += __shfl_xor(acc, 1);
    acc += __shfl_xor(acc, 2);
    acc += __shfl_xor(acc, 4);
    if (lane == 0) s_out[e] = acc * 0.125f;   // 1/sqrt(64)
}

// ---------------- softmax + aggregation (one wave per node) ----------------
__global__ __launch_bounds__(256) void agg_kernel(const float* __restrict__ s_sorted,
                                                  const int* __restrict__ ssrc,
                                                  const int* __restrict__ row_off,
                                                  const float* __restrict__ vb,
                                                  const float* __restrict__ skb,
                                                  float* __restrict__ out) {
    int n    = (blockIdx.x * 256 + threadIdx.x) >> 6;
    int lane = threadIdx.x & 63;
    if (n >= N_NODES) return;
    int beg = row_off[n], end = row_off[n + 1];
    float skv = skb[n * 64 + lane];
    float acc = 0.f;
    if (end > beg) {
        float mx = -INFINITY;
        for (int p = beg + lane; p < end; p += 64) mx = fmaxf(mx, s_sorted[p]);
#pragma unroll
        for (int o = 32; o >= 1; o >>= 1) mx = fmaxf(mx, __shfl_xor(mx, o));
        float sm = 0.f;
        for (int p = beg + lane; p < end; p += 64) sm += __expf(s_sorted[p] - mx);
#pragma unroll
        for (int o = 32; o >= 1; o >>= 1) sm += __shfl_xor(sm, o);
        float inv = 1.f / sm;
        int p = beg;
        for (; p + 1 < end; p += 2) {
            float w0 = __expf(s_sorted[p] - mx);
            float w1 = __expf(s_sorted[p + 1] - mx);
            int   s0 = ssrc[p], s1 = ssrc[p + 1];
            float v0 = vb[s0 * 64 + lane];
            float v1 = vb[s1 * 64 + lane];
            acc = fmaf(w0, v0, acc);
            acc = fmaf(w1, v1, acc);
        }
        if (p < end) acc = fmaf(__expf(s_sorted[p] - mx), vb[ssrc[p] * 64 + lane], acc);
        acc *= inv;
    }
    out[n * 64 + lane] = acc + skv;
}

// ---------------- batchnorm stats ----------------
__global__ __launch_bounds__(256) void bn_stats_kernel(const float* __restrict__ h,
                                                       float* __restrict__ sums) {
    __shared__ float red[256], red2[256];
    int t = threadIdx.x;
    int d = t & 63, part = t >> 6;
    float s = 0.f, s2 = 0.f;
    for (int r = blockIdx.x * 4 + part; r < N_NODES; r += gridDim.x * 4) {
        float v = h[r * 64 + d];
        s += v;
        s2 = fmaf(v, v, s2);
    }
    red[t] = s; red2[t] = s2;
    __syncthreads();
    if (t < 64) {
        s  = red[t] + red[t + 64] + red[t + 128] + red[t + 192];
        s2 = red2[t] + red2[t + 64] + red2[t + 128] + red2[t + 192];
        atomicAdd(&sums[t], s);
        atomicAdd(&sums[64 + t], s2);
    }
}

__global__ void bn_final_kernel(const float* __restrict__ sums, float* __restrict__ bnp) {
    int d = threadIdx.x;
    if (d < 64) {
        float mean = sums[d] * (1.0f / N_NODES);
        float var  = sums[64 + d] * (1.0f / N_NODES) - mean * mean;
        bnp[d]      = mean;
        bnp[64 + d] = rsqrtf(var + EPSV);
    }
}

// ---------------- launch ----------------

extern "C" void kernel_launch(void* const* d_in, const int* in_sizes, int n_in,
                              void* d_out, int out_size, void* d_ws, size_t ws_size,
                              hipStream_t stream) {
    const float* x     = (const float*)d_in[0];
    const int*   ei    = (const int*)d_in[1];
    const float* Wq    = (const float*)d_in[2];
    const float* bq    = (const float*)d_in[3];
    const float* Wk    = (const float*)d_in[4];
    const float* bk    = (const float*)d_in[5];
    const float* Wv    = (const float*)d_in[6];
    const float* bv    = (const float*)d_in[7];
    const float* Ws    = (const float*)d_in[8];
    const float* bs    = (const float*)d_in[9];
    const float* gamma = (const float*)d_in[10];
    const float* beta  = (const float*)d_in[11];
    float* out = (float*)d_out;

    char* wsp = (char*)d_ws;
    size_t off = 0;
    auto alloc = [&](size_t bytes) -> void* {
        void* p = wsp + off;
        off += (bytes + 255) / 256 * 256;
        return p;
    };
    float* qb       = (float*)alloc((size_t)N_NODES * 64 * 4);
    float* kb       = (float*)alloc((size_t)N_NODES * 64 * 4);
    float* vb       = (float*)alloc((size_t)N_NODES * 64 * 4);
    float* skb      = (float*)alloc((size_t)N_NODES * 64 * 4);
    float* hbuf     = (float*)alloc((size_t)N_NODES * 64 * 4);
    float* s_sorted = (float*)alloc((size_t)N_EDGES * 4);
    int*   row_off  = (int*)alloc((size_t)(N_NODES + 1) * 4);
    int*   cursor   = (int*)alloc((size_t)N_NODES * 4);
    int*   ssrc     = (int*)alloc((size_t)N_EDGES * 4);
    int*   sdst     = (int*)alloc((size_t)N_EDGES * 4);
    float* sums     = (float*)alloc(128 * 4);
    float* bnp      = (float*)alloc(128 * 4);

    const int* src = ei;
    const int* dst = ei + N_EDGES;

    // CSR build (edge_index is layer-invariant)
    hipMemsetAsync(cursor, 0, N_NODES * 4, stream);
    count_kernel<<<(N_EDGES + 255) / 256, 256, 0, stream>>>(dst, cursor);
    scan_kernel<<<1, 1024, 0, stream>>>(cursor, row_off);
    scatter_kernel<<<(N_EDGES + 255) / 256, 256, 0, stream>>>(src, dst, cursor, ssrc, sdst);

    const int proj_grid = (N_NODES + PROJ_NT - 1) / PROJ_NT;
    const int edge_grid = (N_EDGES * 8 + 255) / 256;
    const int agg_grid  = (N_NODES + 3) / 4;

    for (int l = 0; l < 3; l++) {
        const float* hin = (l == 0) ? x : hbuf;
        if (l == 0) {
            proj_kernel<false><<<proj_grid, 256, 0, stream>>>(
                hin, Wq, Wk, Wv, Ws, bq, bk, bv, bs,
                bnp, gamma, beta, qb, kb, vb, skb);
        } else {
            proj_kernel<true><<<proj_grid, 256, 0, stream>>>(
                hin, Wq + l * 4096, Wk + l * 4096, Wv + l * 4096, Ws + l * 4096,
                bq + l * 64, bk + l * 64, bv + l * 64, bs + l * 64,
                bnp, gamma + (l - 1) * 64, beta + (l - 1) * 64, qb, kb, vb, skb);
        }
        edge_kernel<<<edge_grid, 256, 0, stream>>>(qb, kb, sdst, ssrc, s_sorted);
        float* o = (l == 2) ? out : hbuf;
        agg_kernel<<<agg_grid, 256, 0, stream>>>(s_sorted, ssrc, row_off, vb, skb, o);
        if (l < 2) {
            hipMemsetAsync(sums, 0, 128 * 4, stream);
            bn_stats_kernel<<<256, 256, 0, stream>>>(hbuf, sums);
            bn_final_kernel<<<1, 64, 0, stream>>>(sums, bnp);
        }
    }
}